// Round 11
// baseline (258.319 us; speedup 1.0000x reference)
//
#include <hip/hip_runtime.h>
#include <hip/hip_bf16.h>
#include <math.h>

#define B_ 2
#define L_ 2048
#define DM_ 1024
#define DC_ 512
#define NH_ 8
#define DH_ 64
#define MR_ (B_*L_)   // 4096 rows
#define BH_ (B_*NH_)  // 16

typedef unsigned short u16;
typedef unsigned int u32;
typedef __attribute__((ext_vector_type(8))) short bf16x8;
typedef __attribute__((ext_vector_type(4))) float f32x4;

static __device__ __forceinline__ u16 f2bf(float x) {
  union { float f; u32 u; } v; v.f = x;
  u32 r = (v.u + 0x7fffu + ((v.u >> 16) & 1u)) >> 16;  // RNE
  return (u16)r;
}
static __device__ __forceinline__ float bf2f(u16 x) {
  union { u32 u; float f; } v; v.u = ((u32)x) << 16;
  return v.f;
}

// ---------------------------------------------------------------------------
// One-shot fp32 -> bf16 conversion: x1, Wq, Wk, Wst, Wout.
// ---------------------------------------------------------------------------
__global__ __launch_bounds__(256) void cvt_k(
    const float* __restrict__ src,
    const float* __restrict__ Wq, const float* __restrict__ Wk,
    const float* __restrict__ Wst, const float* __restrict__ Wout,
    u16* __restrict__ x1b, u16* __restrict__ Wqb, u16* __restrict__ Wkb,
    u16* __restrict__ Wstb, u16* __restrict__ Woutb)
{
  int v = blockIdx.x * 256 + threadIdx.x;
  if (v < 524288) {
    const int m = v >> 7, c = (v & 127) << 2;
    float4 f = *(const float4*)(src + (size_t)m * DM_ + c);
    *(ushort4*)(x1b + (size_t)m * DC_ + c) =
        make_ushort4(f2bf(f.x), f2bf(f.y), f2bf(f.z), f2bf(f.w));
    return;
  }
  v -= 524288;
  const float* sp; u16* dp;
  if (v < 65536)       { sp = Wq;   dp = Wqb; }
  else if (v < 131072) { sp = Wk;   dp = Wkb;   v -= 65536; }
  else if (v < 196608) { sp = Wst;  dp = Wstb;  v -= 131072; }
  else                 { sp = Wout; dp = Woutb; v -= 196608; }
  float4 f = *(const float4*)(sp + (size_t)v * 4);
  *(ushort4*)(dp + (size_t)v * 4) =
      make_ushort4(f2bf(f.x), f2bf(f.y), f2bf(f.z), f2bf(f.w));
}

// ---------------------------------------------------------------------------
// Fragmentize K (unchanged from round 10): Kf (QK B-frags, in place over Kh)
// and Gf (PV B-frags = K^T frags). All attn frag loads -> base + lane*16B.
// ---------------------------------------------------------------------------
__global__ __launch_bounds__(256) void frag_k(const u16* __restrict__ Kh,
                                              u16* __restrict__ Kf,
                                              u16* __restrict__ Gf)
{
  __shared__ u16 T[64*72];
  const int tid = threadIdx.x;
  const int bh = blockIdx.x >> 5, mblk = blockIdx.x & 31;
  const int m0 = mblk << 6;
  const u16* Kb = Kh + ((size_t)bh * L_ + m0) * DH_;
  {
    const int r = tid >> 2, c = (tid & 3) << 4;
    *(bf16x8*)&T[r*72 + c]     = *(const bf16x8*)(Kb + (size_t)r * DH_ + c);
    *(bf16x8*)&T[r*72 + c + 8] = *(const bf16x8*)(Kb + (size_t)r * DH_ + c + 8);
  }
  __syncthreads();
#pragma unroll
  for (int i = 0; i < 2; ++i) {
    const int s = tid + (i << 8);
    const int mt_l = s >> 7, ks = (s >> 6) & 1, lane = s & 63;
    const int lr = lane & 15, lg = lane >> 4;
    bf16x8 v = *(bf16x8*)&T[(mt_l*16 + lr)*72 + ks*32 + lg*8];
    *(bf16x8*)(Kf + ((size_t)((bh*128 + mblk*4 + mt_l)*2 + ks)*64 + lane)*8) = v;
  }
#pragma unroll
  for (int i = 0; i < 2; ++i) {
    const int s = tid + (i << 8);
    const int ds = s >> 7, ks = (s >> 6) & 1, lane = s & 63;
    const int lr = lane & 15, lg = lane >> 4;
    bf16x8 v;
#pragma unroll
    for (int j = 0; j < 8; ++j)
      v[j] = (short)T[(ks*32 + lg*8 + j)*72 + ds*16 + lr];
    *(bf16x8*)(Gf + ((size_t)(((bh*4 + ds)*32 + mblk)*2 + ks)*64 + lane)*8) = v;
  }
}

// ---------------------------------------------------------------------------
// bf16 MFMA GEMM: C = A @ W^T + bias. (unchanged)
// ---------------------------------------------------------------------------
template<int MODE, int BN>
__global__ __launch_bounds__(256) void mgemm_k(
    const u16* __restrict__ A, const u16* __restrict__ A2,
    const u16* __restrict__ W, const float* __restrict__ bias,
    const float* __restrict__ src, u16* __restrict__ Ob,
    float* __restrict__ Of, int Ndim, int Kdim)
{
  constexpr int MF = (BN == 128) ? 4 : 2;
  constexpr int WC = BN / 64;
  __shared__ u16 As[128 * 40];
  __shared__ u16 Ws[BN * 40];
  const int tid = threadIdx.x;
  const int wid = tid >> 6, lane = tid & 63;
  const int lr = lane & 15, lg = lane >> 4;
  const int wr = wid / WC, wc = wid % WC;
  const int m0 = blockIdx.y << 7;
  const int n0 = blockIdx.x * BN;

  f32x4 acc[MF][4];
#pragma unroll
  for (int mi = 0; mi < MF; ++mi)
#pragma unroll
    for (int ni = 0; ni < 4; ++ni)
      acc[mi][ni] = (f32x4){0.f, 0.f, 0.f, 0.f};

  for (int k0 = 0; k0 < Kdim; k0 += 32) {
    {
      const int row = tid >> 1, seg = (tid & 1) << 4;
      const u16* ap;
      if (MODE == 2)
        ap = (k0 < 512) ? A  + (size_t)(m0 + row) * 512 + k0 + seg
                        : A2 + (size_t)(m0 + row) * 512 + (k0 - 512) + seg;
      else
        ap = A + (size_t)(m0 + row) * Kdim + k0 + seg;
      *(bf16x8*)&As[row * 40 + seg]     = *(const bf16x8*)ap;
      *(bf16x8*)&As[row * 40 + seg + 8] = *(const bf16x8*)(ap + 8);
    }
    if (BN == 128) {
      const int row = tid >> 1, seg = (tid & 1) << 4;
      const u16* wp = W + (size_t)(n0 + row) * Kdim + k0 + seg;
      *(bf16x8*)&Ws[row * 40 + seg]     = *(const bf16x8*)wp;
      *(bf16x8*)&Ws[row * 40 + seg + 8] = *(const bf16x8*)(wp + 8);
    } else {
      const int row = tid >> 2, seg = (tid & 3) << 3;
      *(bf16x8*)&Ws[row * 40 + seg] =
          *(const bf16x8*)(W + (size_t)(n0 + row) * Kdim + k0 + seg);
    }
    __syncthreads();
    bf16x8 af[MF], bfr[4];
#pragma unroll
    for (int mi = 0; mi < MF; ++mi)
      af[mi] = *(bf16x8*)&As[(wr * (MF * 16) + mi * 16 + lr) * 40 + lg * 8];
#pragma unroll
    for (int ni = 0; ni < 4; ++ni)
      bfr[ni] = *(bf16x8*)&Ws[(wc * 64 + ni * 16 + lr) * 40 + lg * 8];
#pragma unroll
    for (int mi = 0; mi < MF; ++mi)
#pragma unroll
      for (int ni = 0; ni < 4; ++ni)
        acc[mi][ni] = __builtin_amdgcn_mfma_f32_16x16x32_bf16(
            af[mi], bfr[ni], acc[mi][ni], 0, 0, 0);
    __syncthreads();
  }

#pragma unroll
  for (int mi = 0; mi < MF; ++mi)
#pragma unroll
    for (int ni = 0; ni < 4; ++ni)
#pragma unroll
      for (int r = 0; r < 4; ++r) {
        const int m = m0 + wr * (MF * 16) + mi * 16 + lg * 4 + r;
        const int n = n0 + wc * 64 + ni * 16 + lr;
        const float v = acc[mi][ni][r] + bias[n];
        if (MODE == 0) {
          const int b = m >> 11, l = m & (L_ - 1), h = n >> 6, d = n & (DH_ - 1);
          Ob[((size_t)(b * NH_ + h) * L_ + l) * DH_ + d] = f2bf(v);
        } else if (MODE == 1) {
          const float x2 = src[(size_t)m * DM_ + DC_ + n];
          const float s = 1.f / (1.f + __expf(-v));
          Ob[(size_t)m * DC_ + n] = f2bf(s * tanhf(x2) + (1.f - s) * x2);
        } else {
          Of[(size_t)m * Ndim + n] = v;
        }
      }
}

// ---------------------------------------------------------------------------
// Saliency conv1d v2 (unchanged)
// ---------------------------------------------------------------------------
__global__ __launch_bounds__(256) void conv_k(
    const float* __restrict__ src, const float* __restrict__ cw,
    const float* __restrict__ cb, float* __restrict__ sal)
{
  __shared__ float xs[10][532];
  __shared__ float part[8][8][4];
  const int b = blockIdx.y;
  const int l0 = blockIdx.x << 3;
  const int tid = threadIdx.x;
  const int li = tid >> 5;
  const int h  = (tid >> 2) & 7;
  const int cq = tid & 3;
  for (int t = tid; t < 10*128; t += 256) {
    const int r = t >> 7, c4 = (t & 127) << 2;
    const int l = l0 - 1 + r;
    float4 v = make_float4(0.f, 0.f, 0.f, 0.f);
    if (l >= 0 && l < L_)
      v = *(const float4*)(src + (size_t)(b*L_ + l) * DM_ + c4);
    *(float4*)&xs[r][c4 + (c4 >> 5)] = v;
  }
  __syncthreads();
  float acc = 0.f;
  const int cbase = cq << 7;
#pragma unroll 4
  for (int c = 0; c < 128; ++c) {
    const int cc = cbase + c;
    const int col = cc + (cc >> 5);
    const float* w = cw + ((size_t)h * DC_ + cc) * 3;
    acc += xs[li+0][col]*w[0] + xs[li+1][col]*w[1] + xs[li+2][col]*w[2];
  }
  part[li][h][cq] = acc;
  __syncthreads();
  if (tid < 64) {
    const int l2 = tid >> 3, h2 = tid & 7;
    const float s = cb[h2] + part[l2][h2][0] + part[l2][h2][1]
                           + part[l2][h2][2] + part[l2][h2][3];
    sal[(size_t)(b*NH_ + h2) * L_ + l0 + l2] = s;
  }
}

// ---------------------------------------------------------------------------
// MFMA attention v6: m-split x4 for full occupancy. Block = 4 waves, SAME 16
// q-rows; wave wm owns key-quarter [wm*512, wm*512+512) (8 tiles). Grid 2048
// blocks = 8 blocks/CU = 32 waves/CU (was 8). Rowsums: shfl-reduce + LDS
// cross-wave combine (1 barrier). PV: tree combine in LDS (3 barriers).
// Frag loads stay fully coalesced (Kf/Gf fragment-native layouts).
// ---------------------------------------------------------------------------
__global__ __launch_bounds__(256, 8) void attn_k(
    const u16* __restrict__ Qh, const u16* __restrict__ Kf,
    const u16* __restrict__ Gf, const float* __restrict__ sal,
    float* __restrict__ attn, u16* __restrict__ ctxb)
{
  __shared__ u16 Ps[4*16*72];        // per-wave P strips (9.2 KB)
  __shared__ float RsB[4][16];       // rowsum partials (256 B)
  __shared__ float PvB[2][16*64];    // PV combine buffers (8 KB)

  const int tid = threadIdx.x;
  const int wm = tid >> 6, lane = tid & 63;  // wm = key-quarter index
  const int lr = lane & 15, lg = lane >> 4;
  const int lin = blockIdx.x;
  const int swz = (lin & 7) * 256 + (lin >> 3);   // 2048 = 8*256 bijective
  const int bh = swz >> 7, q0 = (swz & 127) << 4;

  const u16* Kfb = Kf + (size_t)bh * 131072;
  const u16* Gfb = Gf + (size_t)bh * 131072;
  const float* salp = sal + (size_t)bh * L_;

  // Q frags: all 4 waves load the same 16 rows (2 KB, L2 broadcast)
  const u16* Qp = Qh + ((size_t)bh * L_ + q0) * DH_;
  bf16x8 qf[2];
  qf[0] = *(const bf16x8*)(Qp + (size_t)lr * DH_ + lg*8);
  qf[1] = *(const bf16x8*)(Qp + (size_t)lr * DH_ + 32 + lg*8);

  // ================= sweep 1: rowsums over this wave's quarter =============
  float rs[4] = {0.f, 0.f, 0.f, 0.f};
  for (int tt = 0; tt < 8; ++tt) {
    const int t = wm*8 + tt, m0 = t << 6;
#pragma unroll
    for (int ms = 0; ms < 4; ++ms) {
      f32x4 acc = {0.f, 0.f, 0.f, 0.f};
      bf16x8 k0 = *(const bf16x8*)(Kfb + ((size_t)((t*4 + ms)*2 + 0)*64 + lane)*8);
      bf16x8 k1 = *(const bf16x8*)(Kfb + ((size_t)((t*4 + ms)*2 + 1)*64 + lane)*8);
      acc = __builtin_amdgcn_mfma_f32_16x16x32_bf16(qf[0], k0, acc, 0, 0, 0);
      acc = __builtin_amdgcn_mfma_f32_16x16x32_bf16(qf[1], k1, acc, 0, 0, 0);
      const float sl = salp[m0 + ms*16 + lr];
#pragma unroll
      for (int r = 0; r < 4; ++r)
        rs[r] += __expf(fmaf(acc[r], 0.125f, sl));
    }
  }
  // reduce over the 16 col-lanes of each group
#pragma unroll
  for (int r = 0; r < 4; ++r) {
    float v = rs[r];
    v += __shfl_xor(v, 1); v += __shfl_xor(v, 2);
    v += __shfl_xor(v, 4); v += __shfl_xor(v, 8);
    rs[r] = v;
  }
  if (lr == 0) {
#pragma unroll
    for (int r = 0; r < 4; ++r) RsB[wm][lg*4 + r] = rs[r];
  }
  __syncthreads();
#pragma unroll
  for (int r = 0; r < 4; ++r) {
    const int row = lg*4 + r;
    rs[r] = 1.0f / (RsB[0][row] + RsB[1][row] + RsB[2][row] + RsB[3][row]);
  }

  // ================= sweep 2: attn store + PV over quarter =================
  f32x4 pvacc[4] = {{0.f,0.f,0.f,0.f},{0.f,0.f,0.f,0.f},
                    {0.f,0.f,0.f,0.f},{0.f,0.f,0.f,0.f}};
  u16* PsW = &Ps[wm*16*72];
  for (int tt = 0; tt < 8; ++tt) {
    const int t = wm*8 + tt, m0 = t << 6;
#pragma unroll
    for (int ms = 0; ms < 4; ++ms) {
      f32x4 acc = {0.f, 0.f, 0.f, 0.f};
      bf16x8 k0 = *(const bf16x8*)(Kfb + ((size_t)((t*4 + ms)*2 + 0)*64 + lane)*8);
      bf16x8 k1 = *(const bf16x8*)(Kfb + ((size_t)((t*4 + ms)*2 + 1)*64 + lane)*8);
      acc = __builtin_amdgcn_mfma_f32_16x16x32_bf16(qf[0], k0, acc, 0, 0, 0);
      acc = __builtin_amdgcn_mfma_f32_16x16x32_bf16(qf[1], k1, acc, 0, 0, 0);
      const float sl = salp[m0 + ms*16 + lr];
#pragma unroll
      for (int r = 0; r < 4; ++r) {
        const float ph = __expf(fmaf(acc[r], 0.125f, sl)) * rs[r];
        PsW[(lg*4 + r)*72 + ms*16 + lr] = f2bf(ph);
      }
    }
    // attn store: own strip (same-wave LDS, no barrier), coalesced float4
    {
      const int qr = lane >> 2;
      const int mseg = (lane & 3) << 4;
      bf16x8 v0 = *(bf16x8*)&PsW[qr*72 + mseg];
      bf16x8 v1 = *(bf16x8*)&PsW[qr*72 + mseg + 8];
      float* dst = attn + ((size_t)bh * L_ + q0 + qr) * L_ + m0 + mseg;
#pragma unroll
      for (int u = 0; u < 2; ++u) {
        bf16x8 v = u ? v1 : v0;
        float4 f0 = make_float4(bf2f((u16)v[0]), bf2f((u16)v[1]),
                                bf2f((u16)v[2]), bf2f((u16)v[3]));
        float4 f1 = make_float4(bf2f((u16)v[4]), bf2f((u16)v[5]),
                                bf2f((u16)v[6]), bf2f((u16)v[7]));
        *(float4*)(dst + u*8)     = f0;
        *(float4*)(dst + u*8 + 4) = f1;
      }
    }
    // PV partial: pvacc += P @ K (B-frags from Gf)
#pragma unroll
    for (int ks = 0; ks < 2; ++ks) {
      bf16x8 pa = *(bf16x8*)&PsW[lr*72 + ks*32 + lg*8];
#pragma unroll
      for (int ds = 0; ds < 4; ++ds) {
        bf16x8 g = *(const bf16x8*)(Gfb + ((size_t)((ds*32 + t)*2 + ks)*64 + lane)*8);
        pvacc[ds] = __builtin_amdgcn_mfma_f32_16x16x32_bf16(pa, g, pvacc[ds], 0, 0, 0);
      }
    }
  }

  // ================= tree combine of pvacc across the 4 waves ==============
  if (wm & 1) {
    float* d = &PvB[wm >> 1][0];
#pragma unroll
    for (int ds = 0; ds < 4; ++ds)
#pragma unroll
      for (int r = 0; r < 4; ++r)
        d[(lg*4 + r)*64 + ds*16 + lr] = pvacc[ds][r];
  }
  __syncthreads();
  if (!(wm & 1)) {
    const float* s = &PvB[wm >> 1][0];
#pragma unroll
    for (int ds = 0; ds < 4; ++ds)
#pragma unroll
      for (int r = 0; r < 4; ++r)
        pvacc[ds][r] += s[(lg*4 + r)*64 + ds*16 + lr];
  }
  __syncthreads();
  if (wm == 2) {
    float* d = &PvB[0][0];
#pragma unroll
    for (int ds = 0; ds < 4; ++ds)
#pragma unroll
      for (int r = 0; r < 4; ++r)
        d[(lg*4 + r)*64 + ds*16 + lr] = pvacc[ds][r];
  }
  __syncthreads();
  if (wm == 0) {
    const float* s = &PvB[0][0];
    const int b = bh >> 3, h = bh & 7;
#pragma unroll
    for (int ds = 0; ds < 4; ++ds)
#pragma unroll
      for (int r = 0; r < 4; ++r) {
        const float v = pvacc[ds][r] + s[(lg*4 + r)*64 + ds*16 + lr];
        ctxb[((size_t)(b*L_ + q0 + lg*4 + r)) * DC_ + h*DH_ + ds*16 + lr] = f2bf(v);
      }
  }
}

// ---------------------------------------------------------------------------
extern "C" void kernel_launch(void* const* d_in, const int* in_sizes, int n_in,
                              void* d_out, int out_size, void* d_ws, size_t ws_size,
                              hipStream_t stream)
{
  const float* src   = (const float*)d_in[0];
  const float* Wq    = (const float*)d_in[1];
  const float* bq    = (const float*)d_in[2];
  const float* Wk    = (const float*)d_in[3];
  const float* bk    = (const float*)d_in[4];
  const float* convw = (const float*)d_in[5];
  const float* convb = (const float*)d_in[6];
  const float* Wst   = (const float*)d_in[7];
  const float* bst   = (const float*)d_in[8];
  const float* Wout  = (const float*)d_in[9];
  const float* bout  = (const float*)d_in[10];

  float* out  = (float*)d_out;                 // fp32
  float* attn = out + (size_t)MR_ * DM_;

  u16*   x1b   = (u16*)d_ws;                    // [4096][512]
  u16*   Kh    = x1b   + (size_t)MR_ * DC_;     // K heads; becomes Kf in place
  u16*   Qh    = Kh    + (size_t)BH_ * L_ * DH_;
  u16*   Gf    = Qh    + (size_t)BH_ * L_ * DH_;// [16][4][32][2][64][8]
  u16*   ctxb  = Gf    + (size_t)BH_ * L_ * DH_;// [4096][512]
  u16*   y2b   = ctxb  + (size_t)MR_ * DC_;     // [4096][512]
  u16*   Wqb   = y2b   + (size_t)MR_ * DC_;     // [512][512]
  u16*   Wkb   = Wqb   + (size_t)DC_ * DC_;
  u16*   Wstb  = Wkb   + (size_t)DC_ * DC_;
  u16*   Woutb = Wstb  + (size_t)DC_ * DC_;     // [1024][1024]
  float* salb  = (float*)(Woutb + (size_t)DM_ * DM_); // [16][2048]

  (void)in_sizes; (void)n_in; (void)out_size; (void)ws_size;

  cvt_k<<<dim3(3840), 256, 0, stream>>>(src, Wq, Wk, Wst, Wout,
                                        x1b, Wqb, Wkb, Wstb, Woutb);
  mgemm_k<0,64><<<dim3(8, 32), 256, 0, stream>>>(x1b, nullptr, Wqb, bq, nullptr, Qh, nullptr, DC_, DC_);
  mgemm_k<0,64><<<dim3(8, 32), 256, 0, stream>>>(x1b, nullptr, Wkb, bk, nullptr, Kh, nullptr, DC_, DC_);
  frag_k<<<dim3(512), 256, 0, stream>>>(Kh, Kh /*in-place Kf*/, Gf);
  conv_k<<<dim3(L_/8, B_), 256, 0, stream>>>(src, convw, convb, salb);
  attn_k<<<dim3(2048), 256, 0, stream>>>(Qh, Kh /*Kf*/, Gf, salb, attn, ctxb);
  mgemm_k<1,64><<<dim3(8, 32), 256, 0, stream>>>(ctxb, nullptr, Wstb, bst, src, y2b, nullptr, DC_, DC_);
  mgemm_k<2,128><<<dim3(8, 32), 256, 0, stream>>>(x1b, y2b, Woutb, bout, nullptr, nullptr, out, DM_, DM_);
}